// Round 8
// baseline (364.536 us; speedup 1.0000x reference)
//
#include <hip/hip_runtime.h>
#include <cstdint>

// ---------------------------------------------------------------------------
// DeepSpeedSelfAttention fused: LN -> QKV GEMM -> flash attention -> out proj
// B=4 S=2048 H=1024 HEADS=16 DHEAD=64. bf16 MFMA 16x16x32 everywhere.
// R11 = controlled split of R10's pair:
//  KEEP (b): k_vt deleted, V^T bf16 store folded into k_gemm<0> part==2
//            epilogue (pure index algebra, bit-identical values).
//  REVERT (a): mask fast path removed; k_attn restored to the byte-exact
//            R9 version (single cvt_pk/permlane block, straight-line).
// Evidence: every kernel with ONE straight-line permlane-swap block passed
// bit-exactly (R5/R8/R9); every kernel DUPLICATING it failed with small
// context errors (R6 ping-pong 0.243, R10 branch arms 0.141). Suspected
// if-conversion/regalloc interaction with cross-lane permlane swaps.
// BANNED: duplicated permlane-swap blocks; R6 pipeline.
// Outputs: [0] out_proj [1] key [2] value [3] context (f32 each).
// ---------------------------------------------------------------------------

typedef __attribute__((ext_vector_type(8))) short short8;
typedef __attribute__((ext_vector_type(4))) short short4v;
typedef __attribute__((ext_vector_type(4))) float floatx4;

#define BSH 8388608
#define PART_STRIDE 8388608
#define LOG2E 1.4426950408889634f

static __device__ __forceinline__ short f2bf(float f) {  // RNE
  union { float f; uint32_t u; } v; v.f = f;
  uint32_t r = v.u + 0x7fffu + ((v.u >> 16) & 1u);
  return (short)(r >> 16);
}

// async global->LDS, width 16. LDS dest = wave-uniform base + lane*16.
typedef __attribute__((address_space(1))) void gas_t;
typedef __attribute__((address_space(3))) void las_t;
static __device__ __forceinline__ void async16(const void* g, const void* l) {
  __builtin_amdgcn_global_load_lds((gas_t*)(uintptr_t)g,
                                   (las_t*)(uint32_t)(uintptr_t)l, 16, 0, 0);
}

// pack 2 f32 -> 1 dword of 2 bf16 (lo = a, hi = b)
static __device__ __forceinline__ uint32_t cvt_pk_bf16(float a, float b) {
  uint32_t r;
  asm("v_cvt_pk_bf16_f32 %0, %1, %2" : "=v"(r) : "v"(a), "v"(b));
  return r;
}
// vdst lanes[32:63] <-> vsrc lanes[0:31]
static __device__ __forceinline__ void swap32(uint32_t& a, uint32_t& b) {
  asm("v_permlane32_swap_b32 %0, %1" : "+v"(a), "+v"(b));
}
// vdst odd 16-rows <-> vsrc even 16-rows (16-31<->0-15, 48-63<->32-47)
static __device__ __forceinline__ void swap16(uint32_t& a, uint32_t& b) {
  asm("v_permlane16_swap_b32 %0, %1" : "+v"(a), "+v"(b));
}
static __device__ __forceinline__ short8 s8_from(uint32_t a, uint32_t b,
                                                 uint32_t c, uint32_t d) {
  union { uint32_t u[4]; short8 s; } t;
  t.u[0] = a; t.u[1] = b; t.u[2] = c; t.u[3] = d;
  return t.s;
}

// ---- fp32 -> bf16 weight conversion ---------------------------------------
__global__ __launch_bounds__(256) void k_convert(const float4* __restrict__ wqkv,
                                                 const float4* __restrict__ ow,
                                                 short4v* __restrict__ dq,
                                                 short4v* __restrict__ dow) {
  const int n1 = (3072 * 1024) / 4, n2 = (1024 * 1024) / 4;
  for (int i = blockIdx.x * 256 + threadIdx.x; i < n1 + n2; i += gridDim.x * 256) {
    float4 v = (i < n1) ? wqkv[i] : ow[i - n1];
    short4v s;
    s[0] = f2bf(v.x); s[1] = f2bf(v.y); s[2] = f2bf(v.z); s[3] = f2bf(v.w);
    if (i < n1) dq[i] = s; else dow[i - n1] = s;
  }
}

// ---- LayerNorm: one block per row of 1024, bf16 out ------------------------
__global__ __launch_bounds__(256) void k_ln(const float* __restrict__ x,
                                            const float* __restrict__ w,
                                            const float* __restrict__ bb,
                                            short* __restrict__ out) {
  const int row = blockIdx.x, t = threadIdx.x;
  float4 v = ((const float4*)(x + row * 1024))[t];
  float s = v.x + v.y + v.z + v.w;
  float sq = v.x * v.x + v.y * v.y + v.z * v.z + v.w * v.w;
#pragma unroll
  for (int off = 32; off; off >>= 1) { s += __shfl_down(s, off); sq += __shfl_down(sq, off); }
  __shared__ float ls[4], lq[4];
  if ((t & 63) == 0) { ls[t >> 6] = s; lq[t >> 6] = sq; }
  __syncthreads();
  s = ls[0] + ls[1] + ls[2] + ls[3];
  sq = lq[0] + lq[1] + lq[2] + lq[3];
  float mu = s * (1.0f / 1024.0f);
  float var = sq * (1.0f / 1024.0f) - mu * mu;
  float rs = rsqrtf(fmaxf(var, 0.0f) + 1e-12f);
  float4 wv = ((const float4*)w)[t];
  float4 bv = ((const float4*)bb)[t];
  short4v o;
  o[0] = f2bf((v.x - mu) * rs * wv.x + bv.x);
  o[1] = f2bf((v.y - mu) * rs * wv.y + bv.y);
  o[2] = f2bf((v.z - mu) * rs * wv.z + bv.z);
  o[3] = f2bf((v.w - mu) * rs * wv.w + bv.w);
  ((short4v*)out)[row * 256 + t] = o;
}

// ---- bf16 GEMM C[M,N] = A[M,K] @ Bm[N,K]^T, 256x128x64, 512 thr, 8 waves ---
// Single-barrier double-buffered K-loop; per K-tile per wave: 32 MFMA,
// 16 ds_read_b128; staging = 6 async16/thread into the inactive buffer.
// MODE 0: QKV epilogue. q: bf16 head-layout pre-scaled by 0.125*log2e.
//         k: bf16 head-layout + fp32 out[1]. v: fp32 out[2] + bf16 V^T
//         (folded k_vt: 4 consecutive-s bf16 = one 8B store).
// MODE 1: plain fp32 store.
template <int MODE>
__global__ __launch_bounds__(512, 2) void k_gemm(const short* __restrict__ A,
                                                 const short* __restrict__ Bm,
                                                 const float* __restrict__ bias,
                                                 float* __restrict__ out,
                                                 short* __restrict__ qkvh,
                                                 short* __restrict__ vtout,
                                                 int K, int N) {
  __shared__ short As[2][256 * 64];   // 2 x 32 KB
  __shared__ short Bs[2][128 * 64];   // 2 x 16 KB
  const int tid = threadIdx.x, lane = tid & 63, w = tid >> 6;
  const int quad = lane >> 4, l15 = lane & 15;
  const int wm = w >> 1, wn = w & 1;             // 4 M-waves x 2 N-waves
  const int m0 = blockIdx.y * 256, n0 = blockIdx.x * 128;
  const int srow = tid >> 3;                     // [0,64) staging row in unit
  const int sc8 = (tid & 7) ^ (srow & 7);        // pre-swizzled 16B chunk

  floatx4 acc[4][4] = {};

  auto stage = [&](int kt, int bi) {
    const short* asrc = &A[(size_t)(m0 + srow) * K + kt * 64 + sc8 * 8];
#pragma unroll
    for (int u = 0; u < 4; u++)                  // A: 4 units of 64 rows
      async16(asrc + (size_t)u * 64 * K, &As[bi][u * 4096 + tid * 8]);
    const short* bsrc = &Bm[(size_t)(n0 + srow) * K + kt * 64 + sc8 * 8];
#pragma unroll
    for (int u = 0; u < 2; u++)                  // B: 2 units of 64 rows
      async16(bsrc + (size_t)u * 64 * K, &Bs[bi][u * 4096 + tid * 8]);
  };

  stage(0, 0);
  const int NT = K >> 6;                         // 16 K-tiles
  for (int kt = 0; kt < NT; kt++) {
    const int cur = kt & 1;
    __syncthreads();                             // buf[cur] resident
    if (kt + 1 < NT) stage(kt + 1, cur ^ 1);
#pragma unroll
    for (int ks = 0; ks < 2; ks++) {
      short8 af[4], bf[4];
#pragma unroll
      for (int m = 0; m < 4; m++) {
        const int r = wm * 64 + m * 16 + l15;
        af[m] = *(const short8*)&As[cur][r * 64 + (((ks * 4 + quad) ^ (r & 7)) * 8)];
      }
#pragma unroll
      for (int n = 0; n < 4; n++) {
        const int r = wn * 64 + n * 16 + l15;
        bf[n] = *(const short8*)&Bs[cur][r * 64 + (((ks * 4 + quad) ^ (r & 7)) * 8)];
      }
#pragma unroll
      for (int m = 0; m < 4; m++)
#pragma unroll
        for (int n = 0; n < 4; n++)
          acc[m][n] = __builtin_amdgcn_mfma_f32_16x16x32_bf16(af[m], bf[n], acc[m][n], 0, 0, 0);
    }
  }

  const int grB = m0 + wm * 64, gcB = n0 + wn * 64;
  const float QS = 0.125f * LOG2E;
#pragma unroll
  for (int m = 0; m < 4; m++) {
#pragma unroll
    for (int n = 0; n < 4; n++) {
      int gc = gcB + n * 16 + l15;
      if (MODE == 0) {
        float bv = bias[gc];
        int part = gc >> 10, within = gc & 1023;
        int head = within >> 6, dd = within & 63;
        short4v vv;
#pragma unroll
        for (int reg = 0; reg < 4; reg++) {
          int gr = grB + m * 16 + quad * 4 + reg;
          float val = acc[m][n][reg] + bv;
          int b_ = gr >> 11, s_ = gr & 2047;
          int hs = (b_ * 16 + head);
          if (part == 0) {
            qkvh[(hs * 2048 + s_) * 64 + dd] = f2bf(val * QS);
          } else if (part == 1) {
            qkvh[PART_STRIDE + (hs * 2048 + s_) * 64 + dd] = f2bf(val);
            out[BSH + gr * 1024 + within] = val;
          } else {
            out[2 * BSH + gr * 1024 + within] = val;
            vv[reg] = f2bf(val);
          }
        }
        if (part == 2) {
          const int gr0 = grB + m * 16 + quad * 4;   // 4 consecutive s, no
          const int b0 = gr0 >> 11, s0 = gr0 & 2047; // 2048-boundary cross
          *(short4v*)&vtout[(size_t)((b0 * 16 + head) * 64 + dd) * 2048 + s0] = vv;
        }
      } else {
#pragma unroll
        for (int reg = 0; reg < 4; reg++) {
          int gr = grB + m * 16 + quad * 4 + reg;
          out[gr * N + gc] = acc[m][n][reg];
        }
      }
    }
  }
}

// ---- flash attention (byte-exact R9, verified): 1D grid 1024, XCD-swizzled -
// wid = (bid&7)*128 + (bid>>3): each XCD owns 8 complete (h,b) pairs x 16 qt
// tiles; per-XCD K/V set = 4MB = L2 (FETCH 139->24.7MB measured). Swapped
// QK^T, in-register P routing (SINGLE cvt_pk + permlane block), no online
// max, ones-MFMA row sums.
__global__ __launch_bounds__(256, 4) void k_attn(const short* __restrict__ qkvh,
                                                 const float* __restrict__ mask,
                                                 float* __restrict__ ctx_out,
                                                 short* __restrict__ ctx_bf) {
  const int bid = blockIdx.x;
  const int wid = (bid & 7) * 128 + (bid >> 3);
  const int qt = wid & 15, h = (wid >> 4) & 15, b = wid >> 8;
  const int tid = threadIdx.x, lane = tid & 63, w = tid >> 6;
  const int quad = lane >> 4, l15 = lane & 15;
  __shared__ short Ks[2][64 * 64];
  __shared__ short Vt[2][64 * 64];
  const short* qg = qkvh + (size_t)(b * 16 + h) * 2048 * 64;
  const short* kg = qg + PART_STRIDE;
  const short* vg = qkvh + 2 * PART_STRIDE + (size_t)(b * 16 + h) * 64 * 2048;  // [d][s]
  const float* mb = mask + b * 2048;

  // Q fragments: 2 row-tiles x 2 d-halves (B-operand of the swapped MFMA)
  short8 qf[2][2];
#pragma unroll
  for (int rt = 0; rt < 2; rt++) {
    const int qr = qt * 128 + w * 32 + rt * 16 + l15;
#pragma unroll
    for (int ks = 0; ks < 2; ks++)
      qf[rt][ks] = *(const short8*)&qg[qr * 64 + ks * 32 + quad * 8];
  }

  short8 ones;
#pragma unroll
  for (int j = 0; j < 8; j++) ones[j] = (short)0x3F80;  // bf16 1.0

  floatx4 accO[2][4] = {};
  floatx4 accL[2] = {};

  auto stage = [&](int kt, int bi) {
#pragma unroll
    for (int r = 0; r < 2; r++) {
      int pb = r * 256 + w * 64;
      int p = pb + lane;
      int row = p >> 3, c = (p & 7) ^ (row & 7);
      async16(&kg[(kt * 64 + row) * 64 + c * 8], &Ks[bi][pb * 8]);
      async16(&vg[row * 2048 + kt * 64 + c * 8], &Vt[bi][pb * 8]);
    }
  };
  stage(0, 0);

  for (int kt = 0; kt < 32; kt++) {
    const int cur = kt & 1;
    __syncthreads();                     // buf[cur] resident; buf[cur^1] free
    if (kt + 1 < 32) stage(kt + 1, cur ^ 1);

    // mask: k on the reg axis -> vector float4 loads
    float mv[4][4];
#pragma unroll
    for (int nt = 0; nt < 4; nt++) {
      float4 t = *(const float4*)&mb[kt * 64 + nt * 16 + quad * 4];
      mv[nt][0] = t.x; mv[nt][1] = t.y; mv[nt][2] = t.z; mv[nt][3] = t.w;
    }

    // S^T = K Q^T  (16 MFMA, 8 kf reads shared across both row-tiles)
    floatx4 sc[2][4] = {};
#pragma unroll
    for (int nt = 0; nt < 4; nt++) {
      const int krow = nt * 16 + l15;
#pragma unroll
      for (int ks = 0; ks < 2; ks++) {
        short8 kf = *(const short8*)&Ks[cur][krow * 64 + (((ks * 4 + quad) ^ (krow & 7)) * 8)];
        sc[0][nt] = __builtin_amdgcn_mfma_f32_16x16x32_bf16(kf, qf[0][ks], sc[0][nt], 0, 0, 0);
        sc[1][nt] = __builtin_amdgcn_mfma_f32_16x16x32_bf16(kf, qf[1][ks], sc[1][nt], 0, 0, 0);
      }
    }

    // p = exp2(s + m*log2e) -> bf16 pack -> cross-quad routing in registers.
    // pa[rt][ks2][m]: A-frag dwords for PV.
    uint32_t pa[2][2][4];
#pragma unroll
    for (int rt = 0; rt < 2; rt++) {
#pragma unroll
      for (int e = 0; e < 2; e++) {
#pragma unroll
        for (int d = 0; d < 2; d++) {
          float p0 = __builtin_amdgcn_exp2f(fmaf(mv[2 * e][2 * d], LOG2E, sc[rt][2 * e][2 * d]));
          float p1 = __builtin_amdgcn_exp2f(fmaf(mv[2 * e][2 * d + 1], LOG2E, sc[rt][2 * e][2 * d + 1]));
          float p2 = __builtin_amdgcn_exp2f(fmaf(mv[2 * e + 1][2 * d], LOG2E, sc[rt][2 * e + 1][2 * d]));
          float p3 = __builtin_amdgcn_exp2f(fmaf(mv[2 * e + 1][2 * d + 1], LOG2E, sc[rt][2 * e + 1][2 * d + 1]));
          uint32_t rE = cvt_pk_bf16(p0, p1);  // X[2e][d]
          uint32_t rO = cvt_pk_bf16(p2, p3);  // X[2e+1][d]
          swap32(rE, rO);
          swap16(rE, rO);
          pa[rt][e][d] = rE;      // A[ks2=e][m=d]
          pa[rt][e][2 + d] = rO;  // A[ks2=e][m=2+d]
        }
      }
    }

    // O += P V ; L += P 1  (20 MFMA, 8 vf reads shared across row-tiles)
#pragma unroll
    for (int ks2 = 0; ks2 < 2; ks2++) {
      short8 pf0 = s8_from(pa[0][ks2][0], pa[0][ks2][1], pa[0][ks2][2], pa[0][ks2][3]);
      short8 pf1 = s8_from(pa[1][ks2][0], pa[1][ks2][1], pa[1][ks2][2], pa[1][ks2][3]);
      accL[0] = __builtin_amdgcn_mfma_f32_16x16x32_bf16(pf0, ones, accL[0], 0, 0, 0);
      accL[1] = __builtin_amdgcn_mfma_f32_16x16x32_bf16(pf1, ones, accL[1], 0, 0, 0);
#pragma unroll
      for (int nt2 = 0; nt2 < 4; nt2++) {
        const int vrow = nt2 * 16 + l15;
        short8 vf = *(const short8*)&Vt[cur][vrow * 64 + (((ks2 * 4 + quad) ^ (vrow & 7)) * 8)];
        accO[0][nt2] = __builtin_amdgcn_mfma_f32_16x16x32_bf16(pf0, vf, accO[0][nt2], 0, 0, 0);
        accO[1][nt2] = __builtin_amdgcn_mfma_f32_16x16x32_bf16(pf1, vf, accO[1][nt2], 0, 0, 0);
      }
    }
  }

  // epilogue: divide by row sums; fp32 -> d_out slice 3, bf16 -> ws
#pragma unroll
  for (int rt = 0; rt < 2; rt++) {
    float inv[4];
#pragma unroll
    for (int reg = 0; reg < 4; reg++) inv[reg] = 1.0f / accL[rt][reg];
#pragma unroll
    for (int nt2 = 0; nt2 < 4; nt2++)
#pragma unroll
      for (int reg = 0; reg < 4; reg++) {
        const int qrow = qt * 128 + w * 32 + rt * 16 + quad * 4 + reg;
        const int col = h * 64 + nt2 * 16 + l15;
        const int gi = (b * 2048 + qrow) * 1024 + col;
        float val = accO[rt][nt2][reg] * inv[reg];
        ctx_out[gi] = val;
        ctx_bf[gi] = f2bf(val);
      }
  }
}

// ---------------------------------------------------------------------------
extern "C" void kernel_launch(void* const* d_in, const int* in_sizes, int n_in,
                              void* d_out, int out_size, void* d_ws, size_t ws_size,
                              hipStream_t stream) {
  const float* x    = (const float*)d_in[0];
  const float* mask = (const float*)d_in[1];
  const float* nw   = (const float*)d_in[2];
  const float* nb   = (const float*)d_in[3];
  const float* wqkv = (const float*)d_in[4];
  const float* bqkv = (const float*)d_in[5];
  const float* ow   = (const float*)d_in[6];
  float* out = (float*)d_out;
  char* ws = (char*)d_ws;

  // ws layout (bytes): [0,16M) ln_bf16 (aliased later as ctx_bf16);
  // [16M,22.3M) wqkv bf16; [22.3M,24M) ow bf16;
  // [24M,+16M) q head-layout; [+16M,+32M) k head-layout; [+32M,+48M) v^T
  short* lnb   = (short*)ws;
  short* wqkvb = (short*)(ws + 16777216);
  short* owb   = (short*)(ws + 23068672);
  short* qkvh  = (short*)(ws + 25165824);
  short* vt    = qkvh + 2 * (size_t)PART_STRIDE;

  k_convert<<<512, 256, 0, stream>>>((const float4*)wqkv, (const float4*)ow,
                                     (short4v*)wqkvb, (short4v*)owb);
  k_ln<<<8192, 256, 0, stream>>>(x, nw, nb, lnb);
  k_gemm<0><<<dim3(24, 32), 512, 0, stream>>>(lnb, wqkvb, bqkv, out, qkvh, vt, 1024, 3072);
  k_attn<<<1024, 256, 0, stream>>>(qkvh, mask, out + 3 * (size_t)BSH, lnb);
  k_gemm<1><<<dim3(8, 32), 512, 0, stream>>>(lnb, owb, nullptr, out, nullptr, nullptr, 1024, 1024);
}

// Round 9
// 351.206 us; speedup vs baseline: 1.0380x; 1.0380x over previous
//
#include <hip/hip_runtime.h>
#include <cstdint>

// ---------------------------------------------------------------------------
// DeepSpeedSelfAttention fused: LN -> QKV GEMM -> flash attention -> out proj
// B=4 S=2048 H=1024 HEADS=16 DHEAD=64. bf16 MFMA 16x16x32 everywhere.
// R12 = R11 + coalesced V^T epilogue. R11's per-reg V^T store was an 8B/lane
// scatter at 4KB stride (-14us net vs R9). Fix: V-part blocks (bx>=16,
// block-uniform) stash bf16 values into transposed LDS scratch T[col][s]
// (reuses As's 64KB, XOR swizzle s^((col&7)<<3) keeps short8 reads
// contiguous), then write V^T in 512B-contiguous short8 rows. Bit-identical
// values to R11. k_vt stays deleted (64MB re-read + launch saved).
// BANNED: duplicated permlane-swap blocks (R6 0.243 / R10 0.141); R6 pipeline.
// Outputs: [0] out_proj [1] key [2] value [3] context (f32 each).
// ---------------------------------------------------------------------------

typedef __attribute__((ext_vector_type(8))) short short8;
typedef __attribute__((ext_vector_type(4))) short short4v;
typedef __attribute__((ext_vector_type(4))) float floatx4;

#define BSH 8388608
#define PART_STRIDE 8388608
#define LOG2E 1.4426950408889634f

static __device__ __forceinline__ short f2bf(float f) {  // RNE
  union { float f; uint32_t u; } v; v.f = f;
  uint32_t r = v.u + 0x7fffu + ((v.u >> 16) & 1u);
  return (short)(r >> 16);
}

// async global->LDS, width 16. LDS dest = wave-uniform base + lane*16.
typedef __attribute__((address_space(1))) void gas_t;
typedef __attribute__((address_space(3))) void las_t;
static __device__ __forceinline__ void async16(const void* g, const void* l) {
  __builtin_amdgcn_global_load_lds((gas_t*)(uintptr_t)g,
                                   (las_t*)(uint32_t)(uintptr_t)l, 16, 0, 0);
}

// pack 2 f32 -> 1 dword of 2 bf16 (lo = a, hi = b)
static __device__ __forceinline__ uint32_t cvt_pk_bf16(float a, float b) {
  uint32_t r;
  asm("v_cvt_pk_bf16_f32 %0, %1, %2" : "=v"(r) : "v"(a), "v"(b));
  return r;
}
// vdst lanes[32:63] <-> vsrc lanes[0:31]
static __device__ __forceinline__ void swap32(uint32_t& a, uint32_t& b) {
  asm("v_permlane32_swap_b32 %0, %1" : "+v"(a), "+v"(b));
}
// vdst odd 16-rows <-> vsrc even 16-rows (16-31<->0-15, 48-63<->32-47)
static __device__ __forceinline__ void swap16(uint32_t& a, uint32_t& b) {
  asm("v_permlane16_swap_b32 %0, %1" : "+v"(a), "+v"(b));
}
static __device__ __forceinline__ short8 s8_from(uint32_t a, uint32_t b,
                                                 uint32_t c, uint32_t d) {
  union { uint32_t u[4]; short8 s; } t;
  t.u[0] = a; t.u[1] = b; t.u[2] = c; t.u[3] = d;
  return t.s;
}

// ---- fp32 -> bf16 weight conversion ---------------------------------------
__global__ __launch_bounds__(256) void k_convert(const float4* __restrict__ wqkv,
                                                 const float4* __restrict__ ow,
                                                 short4v* __restrict__ dq,
                                                 short4v* __restrict__ dow) {
  const int n1 = (3072 * 1024) / 4, n2 = (1024 * 1024) / 4;
  for (int i = blockIdx.x * 256 + threadIdx.x; i < n1 + n2; i += gridDim.x * 256) {
    float4 v = (i < n1) ? wqkv[i] : ow[i - n1];
    short4v s;
    s[0] = f2bf(v.x); s[1] = f2bf(v.y); s[2] = f2bf(v.z); s[3] = f2bf(v.w);
    if (i < n1) dq[i] = s; else dow[i - n1] = s;
  }
}

// ---- LayerNorm: one block per row of 1024, bf16 out ------------------------
__global__ __launch_bounds__(256) void k_ln(const float* __restrict__ x,
                                            const float* __restrict__ w,
                                            const float* __restrict__ bb,
                                            short* __restrict__ out) {
  const int row = blockIdx.x, t = threadIdx.x;
  float4 v = ((const float4*)(x + row * 1024))[t];
  float s = v.x + v.y + v.z + v.w;
  float sq = v.x * v.x + v.y * v.y + v.z * v.z + v.w * v.w;
#pragma unroll
  for (int off = 32; off; off >>= 1) { s += __shfl_down(s, off); sq += __shfl_down(sq, off); }
  __shared__ float ls[4], lq[4];
  if ((t & 63) == 0) { ls[t >> 6] = s; lq[t >> 6] = sq; }
  __syncthreads();
  s = ls[0] + ls[1] + ls[2] + ls[3];
  sq = lq[0] + lq[1] + lq[2] + lq[3];
  float mu = s * (1.0f / 1024.0f);
  float var = sq * (1.0f / 1024.0f) - mu * mu;
  float rs = rsqrtf(fmaxf(var, 0.0f) + 1e-12f);
  float4 wv = ((const float4*)w)[t];
  float4 bv = ((const float4*)bb)[t];
  short4v o;
  o[0] = f2bf((v.x - mu) * rs * wv.x + bv.x);
  o[1] = f2bf((v.y - mu) * rs * wv.y + bv.y);
  o[2] = f2bf((v.z - mu) * rs * wv.z + bv.z);
  o[3] = f2bf((v.w - mu) * rs * wv.w + bv.w);
  ((short4v*)out)[row * 256 + t] = o;
}

// ---- bf16 GEMM C[M,N] = A[M,K] @ Bm[N,K]^T, 256x128x64, 512 thr, 8 waves ---
// Single-barrier double-buffered K-loop; per K-tile per wave: 32 MFMA,
// 16 ds_read_b128; staging = 6 async16/thread into the inactive buffer.
// MODE 0: QKV epilogue. q: bf16 head-layout pre-scaled by 0.125*log2e.
//         k: bf16 head-layout + fp32 out[1]. v: fp32 out[2] + bf16 V^T via
//         LDS-transposed coalesced stores (V-blocks bx>=16, block-uniform).
// MODE 1: plain fp32 store.
template <int MODE>
__global__ __launch_bounds__(512, 2) void k_gemm(const short* __restrict__ A,
                                                 const short* __restrict__ Bm,
                                                 const float* __restrict__ bias,
                                                 float* __restrict__ out,
                                                 short* __restrict__ qkvh,
                                                 short* __restrict__ vtout,
                                                 int K, int N) {
  __shared__ short As[2][256 * 64];   // 2 x 32 KB (reused as V^T scratch)
  __shared__ short Bs[2][128 * 64];   // 2 x 16 KB
  const int tid = threadIdx.x, lane = tid & 63, w = tid >> 6;
  const int quad = lane >> 4, l15 = lane & 15;
  const int wm = w >> 1, wn = w & 1;             // 4 M-waves x 2 N-waves
  const int m0 = blockIdx.y * 256, n0 = blockIdx.x * 128;
  const int srow = tid >> 3;                     // [0,64) staging row in unit
  const int sc8 = (tid & 7) ^ (srow & 7);        // pre-swizzled 16B chunk

  floatx4 acc[4][4] = {};

  auto stage = [&](int kt, int bi) {
    const short* asrc = &A[(size_t)(m0 + srow) * K + kt * 64 + sc8 * 8];
#pragma unroll
    for (int u = 0; u < 4; u++)                  // A: 4 units of 64 rows
      async16(asrc + (size_t)u * 64 * K, &As[bi][u * 4096 + tid * 8]);
    const short* bsrc = &Bm[(size_t)(n0 + srow) * K + kt * 64 + sc8 * 8];
#pragma unroll
    for (int u = 0; u < 2; u++)                  // B: 2 units of 64 rows
      async16(bsrc + (size_t)u * 64 * K, &Bs[bi][u * 4096 + tid * 8]);
  };

  stage(0, 0);
  const int NT = K >> 6;                         // 16 K-tiles
  for (int kt = 0; kt < NT; kt++) {
    const int cur = kt & 1;
    __syncthreads();                             // buf[cur] resident
    if (kt + 1 < NT) stage(kt + 1, cur ^ 1);
#pragma unroll
    for (int ks = 0; ks < 2; ks++) {
      short8 af[4], bf[4];
#pragma unroll
      for (int m = 0; m < 4; m++) {
        const int r = wm * 64 + m * 16 + l15;
        af[m] = *(const short8*)&As[cur][r * 64 + (((ks * 4 + quad) ^ (r & 7)) * 8)];
      }
#pragma unroll
      for (int n = 0; n < 4; n++) {
        const int r = wn * 64 + n * 16 + l15;
        bf[n] = *(const short8*)&Bs[cur][r * 64 + (((ks * 4 + quad) ^ (r & 7)) * 8)];
      }
#pragma unroll
      for (int m = 0; m < 4; m++)
#pragma unroll
        for (int n = 0; n < 4; n++)
          acc[m][n] = __builtin_amdgcn_mfma_f32_16x16x32_bf16(af[m], bf[n], acc[m][n], 0, 0, 0);
    }
  }

  const int grB = m0 + wm * 64, gcB = n0 + wn * 64;
  const float QS = 0.125f * LOG2E;
  const bool vblk = (MODE == 0) && (n0 >= 2048);  // block-uniform
  short* T = &As[0][0];                           // 64 KB = 256 x 128 shorts
  if (vblk) __syncthreads();                      // K-loop LDS reads done
#pragma unroll
  for (int m = 0; m < 4; m++) {
#pragma unroll
    for (int n = 0; n < 4; n++) {
      int gc = gcB + n * 16 + l15;
      if (MODE == 0) {
        float bv = bias[gc];
        int part = gc >> 10, within = gc & 1023;
        int head = within >> 6, dd = within & 63;
        short4v vv;
#pragma unroll
        for (int reg = 0; reg < 4; reg++) {
          int gr = grB + m * 16 + quad * 4 + reg;
          float val = acc[m][n][reg] + bv;
          int b_ = gr >> 11, s_ = gr & 2047;
          int hs = (b_ * 16 + head);
          if (part == 0) {
            qkvh[(hs * 2048 + s_) * 64 + dd] = f2bf(val * QS);
          } else if (part == 1) {
            qkvh[PART_STRIDE + (hs * 2048 + s_) * 64 + dd] = f2bf(val);
            out[BSH + gr * 1024 + within] = val;
          } else {
            out[2 * BSH + gr * 1024 + within] = val;
            vv[reg] = f2bf(val);
          }
        }
        if (part == 2) {  // stash transposed: T[col][s], XOR-swizzled
          const int col = wn * 64 + n * 16 + l15;        // [0,128)
          const int s0 = wm * 64 + m * 16 + quad * 4;    // [0,256)
          *(short4v*)&T[col * 256 + (s0 ^ ((col & 7) << 3))] = vv;
        }
      } else {
#pragma unroll
        for (int reg = 0; reg < 4; reg++) {
          int gr = grB + m * 16 + quad * 4 + reg;
          out[gr * N + gc] = acc[m][n][reg];
        }
      }
    }
  }

  if (vblk) {  // coalesced V^T writeout: 512B-contiguous short8 rows
    __syncthreads();
    const int b0 = m0 >> 11, sbase = m0 & 2047;
    const int nrel0 = n0 - 2048;
#pragma unroll
    for (int p = 0; p < 8; p++) {
      const int r = p * 16 + (tid >> 5);               // [0,128)
      const int s0r = (tid & 31) * 8;                  // [0,256)
      short8 v8 = *(const short8*)&T[r * 256 + (s0r ^ ((r & 7) << 3))];
      const int nrel = nrel0 + r;
      *(short8*)&vtout[(size_t)((b0 * 16 + (nrel >> 6)) * 64 + (nrel & 63)) * 2048
                       + sbase + s0r] = v8;
    }
  }
}

// ---- flash attention (byte-exact R9, verified): 1D grid 1024, XCD-swizzled -
// wid = (bid&7)*128 + (bid>>3): each XCD owns 8 complete (h,b) pairs x 16 qt
// tiles; per-XCD K/V set = 4MB = L2 (FETCH 139->24.7MB measured). Swapped
// QK^T, in-register P routing (SINGLE cvt_pk + permlane block), no online
// max, ones-MFMA row sums.
__global__ __launch_bounds__(256, 4) void k_attn(const short* __restrict__ qkvh,
                                                 const float* __restrict__ mask,
                                                 float* __restrict__ ctx_out,
                                                 short* __restrict__ ctx_bf) {
  const int bid = blockIdx.x;
  const int wid = (bid & 7) * 128 + (bid >> 3);
  const int qt = wid & 15, h = (wid >> 4) & 15, b = wid >> 8;
  const int tid = threadIdx.x, lane = tid & 63, w = tid >> 6;
  const int quad = lane >> 4, l15 = lane & 15;
  __shared__ short Ks[2][64 * 64];
  __shared__ short Vt[2][64 * 64];
  const short* qg = qkvh + (size_t)(b * 16 + h) * 2048 * 64;
  const short* kg = qg + PART_STRIDE;
  const short* vg = qkvh + 2 * PART_STRIDE + (size_t)(b * 16 + h) * 64 * 2048;  // [d][s]
  const float* mb = mask + b * 2048;

  // Q fragments: 2 row-tiles x 2 d-halves (B-operand of the swapped MFMA)
  short8 qf[2][2];
#pragma unroll
  for (int rt = 0; rt < 2; rt++) {
    const int qr = qt * 128 + w * 32 + rt * 16 + l15;
#pragma unroll
    for (int ks = 0; ks < 2; ks++)
      qf[rt][ks] = *(const short8*)&qg[qr * 64 + ks * 32 + quad * 8];
  }

  short8 ones;
#pragma unroll
  for (int j = 0; j < 8; j++) ones[j] = (short)0x3F80;  // bf16 1.0

  floatx4 accO[2][4] = {};
  floatx4 accL[2] = {};

  auto stage = [&](int kt, int bi) {
#pragma unroll
    for (int r = 0; r < 2; r++) {
      int pb = r * 256 + w * 64;
      int p = pb + lane;
      int row = p >> 3, c = (p & 7) ^ (row & 7);
      async16(&kg[(kt * 64 + row) * 64 + c * 8], &Ks[bi][pb * 8]);
      async16(&vg[row * 2048 + kt * 64 + c * 8], &Vt[bi][pb * 8]);
    }
  };
  stage(0, 0);

  for (int kt = 0; kt < 32; kt++) {
    const int cur = kt & 1;
    __syncthreads();                     // buf[cur] resident; buf[cur^1] free
    if (kt + 1 < 32) stage(kt + 1, cur ^ 1);

    // mask: k on the reg axis -> vector float4 loads
    float mv[4][4];
#pragma unroll
    for (int nt = 0; nt < 4; nt++) {
      float4 t = *(const float4*)&mb[kt * 64 + nt * 16 + quad * 4];
      mv[nt][0] = t.x; mv[nt][1] = t.y; mv[nt][2] = t.z; mv[nt][3] = t.w;
    }

    // S^T = K Q^T  (16 MFMA, 8 kf reads shared across both row-tiles)
    floatx4 sc[2][4] = {};
#pragma unroll
    for (int nt = 0; nt < 4; nt++) {
      const int krow = nt * 16 + l15;
#pragma unroll
      for (int ks = 0; ks < 2; ks++) {
        short8 kf = *(const short8*)&Ks[cur][krow * 64 + (((ks * 4 + quad) ^ (krow & 7)) * 8)];
        sc[0][nt] = __builtin_amdgcn_mfma_f32_16x16x32_bf16(kf, qf[0][ks], sc[0][nt], 0, 0, 0);
        sc[1][nt] = __builtin_amdgcn_mfma_f32_16x16x32_bf16(kf, qf[1][ks], sc[1][nt], 0, 0, 0);
      }
    }

    // p = exp2(s + m*log2e) -> bf16 pack -> cross-quad routing in registers.
    // pa[rt][ks2][m]: A-frag dwords for PV.
    uint32_t pa[2][2][4];
#pragma unroll
    for (int rt = 0; rt < 2; rt++) {
#pragma unroll
      for (int e = 0; e < 2; e++) {
#pragma unroll
        for (int d = 0; d < 2; d++) {
          float p0 = __builtin_amdgcn_exp2f(fmaf(mv[2 * e][2 * d], LOG2E, sc[rt][2 * e][2 * d]));
          float p1 = __builtin_amdgcn_exp2f(fmaf(mv[2 * e][2 * d + 1], LOG2E, sc[rt][2 * e][2 * d + 1]));
          float p2 = __builtin_amdgcn_exp2f(fmaf(mv[2 * e + 1][2 * d], LOG2E, sc[rt][2 * e + 1][2 * d]));
          float p3 = __builtin_amdgcn_exp2f(fmaf(mv[2 * e + 1][2 * d + 1], LOG2E, sc[rt][2 * e + 1][2 * d + 1]));
          uint32_t rE = cvt_pk_bf16(p0, p1);  // X[2e][d]
          uint32_t rO = cvt_pk_bf16(p2, p3);  // X[2e+1][d]
          swap32(rE, rO);
          swap16(rE, rO);
          pa[rt][e][d] = rE;      // A[ks2=e][m=d]
          pa[rt][e][2 + d] = rO;  // A[ks2=e][m=2+d]
        }
      }
    }

    // O += P V ; L += P 1  (20 MFMA, 8 vf reads shared across row-tiles)
#pragma unroll
    for (int ks2 = 0; ks2 < 2; ks2++) {
      short8 pf0 = s8_from(pa[0][ks2][0], pa[0][ks2][1], pa[0][ks2][2], pa[0][ks2][3]);
      short8 pf1 = s8_from(pa[1][ks2][0], pa[1][ks2][1], pa[1][ks2][2], pa[1][ks2][3]);
      accL[0] = __builtin_amdgcn_mfma_f32_16x16x32_bf16(pf0, ones, accL[0], 0, 0, 0);
      accL[1] = __builtin_amdgcn_mfma_f32_16x16x32_bf16(pf1, ones, accL[1], 0, 0, 0);
#pragma unroll
      for (int nt2 = 0; nt2 < 4; nt2++) {
        const int vrow = nt2 * 16 + l15;
        short8 vf = *(const short8*)&Vt[cur][vrow * 64 + (((ks2 * 4 + quad) ^ (vrow & 7)) * 8)];
        accO[0][nt2] = __builtin_amdgcn_mfma_f32_16x16x32_bf16(pf0, vf, accO[0][nt2], 0, 0, 0);
        accO[1][nt2] = __builtin_amdgcn_mfma_f32_16x16x32_bf16(pf1, vf, accO[1][nt2], 0, 0, 0);
      }
    }
  }

  // epilogue: divide by row sums; fp32 -> d_out slice 3, bf16 -> ws
#pragma unroll
  for (int rt = 0; rt < 2; rt++) {
    float inv[4];
#pragma unroll
    for (int reg = 0; reg < 4; reg++) inv[reg] = 1.0f / accL[rt][reg];
#pragma unroll
    for (int nt2 = 0; nt2 < 4; nt2++)
#pragma unroll
      for (int reg = 0; reg < 4; reg++) {
        const int qrow = qt * 128 + w * 32 + rt * 16 + quad * 4 + reg;
        const int col = h * 64 + nt2 * 16 + l15;
        const int gi = (b * 2048 + qrow) * 1024 + col;
        float val = accO[rt][nt2][reg] * inv[reg];
        ctx_out[gi] = val;
        ctx_bf[gi] = f2bf(val);
      }
  }
}

// ---------------------------------------------------------------------------
extern "C" void kernel_launch(void* const* d_in, const int* in_sizes, int n_in,
                              void* d_out, int out_size, void* d_ws, size_t ws_size,
                              hipStream_t stream) {
  const float* x    = (const float*)d_in[0];
  const float* mask = (const float*)d_in[1];
  const float* nw   = (const float*)d_in[2];
  const float* nb   = (const float*)d_in[3];
  const float* wqkv = (const float*)d_in[4];
  const float* bqkv = (const float*)d_in[5];
  const float* ow   = (const float*)d_in[6];
  float* out = (float*)d_out;
  char* ws = (char*)d_ws;

  // ws layout (bytes): [0,16M) ln_bf16 (aliased later as ctx_bf16);
  // [16M,22.3M) wqkv bf16; [22.3M,24M) ow bf16;
  // [24M,+16M) q head-layout; [+16M,+32M) k head-layout; [+32M,+48M) v^T
  short* lnb   = (short*)ws;
  short* wqkvb = (short*)(ws + 16777216);
  short* owb   = (short*)(ws + 23068672);
  short* qkvh  = (short*)(ws + 25165824);
  short* vt    = qkvh + 2 * (size_t)PART_STRIDE;

  k_convert<<<512, 256, 0, stream>>>((const float4*)wqkv, (const float4*)ow,
                                     (short4v*)wqkvb, (short4v*)owb);
  k_ln<<<8192, 256, 0, stream>>>(x, nw, nb, lnb);
  k_gemm<0><<<dim3(24, 32), 512, 0, stream>>>(lnb, wqkvb, bqkv, out, qkvh, vt, 1024, 3072);
  k_attn<<<1024, 256, 0, stream>>>(qkvh, mask, out + 3 * (size_t)BSH, lnb);
  k_gemm<1><<<dim3(8, 32), 512, 0, stream>>>(lnb, owb, nullptr, out, nullptr, nullptr, 1024, 1024);
}